// Round 9
// baseline (109.554 us; speedup 1.0000x reference)
//
#include <hip/hip_runtime.h>
#include <math.h>

#define BLOCK  512
#define NW     (BLOCK / 64)   // 8 waves per block
#define NTILES 8              // L / BLOCK (L = 4096 fixed by harness)

typedef float f32x4 __attribute__((ext_vector_type(4)));

__device__ __forceinline__ float sp(float x) {
    // softplus: max(x,0) + log(1 + exp(-|x|)) — fast intrinsics, huge error budget
    return fmaxf(x, 0.0f) + __logf(1.0f + __expf(-fabsf(x)));
}

// Wave64 inclusive scan (add) on the VALU via DPP (verified rounds 7-8).
__device__ __forceinline__ float wave_scan_f32(float s) {
    s += __int_as_float(__builtin_amdgcn_update_dpp(0, __float_as_int(s), 0x111, 0xf, 0xf, false));
    s += __int_as_float(__builtin_amdgcn_update_dpp(0, __float_as_int(s), 0x112, 0xf, 0xf, false));
    s += __int_as_float(__builtin_amdgcn_update_dpp(0, __float_as_int(s), 0x114, 0xf, 0xf, false));
    s += __int_as_float(__builtin_amdgcn_update_dpp(0, __float_as_int(s), 0x118, 0xf, 0xf, false));
    s += __int_as_float(__builtin_amdgcn_update_dpp(0, __float_as_int(s), 0x142, 0xa, 0xf, false));
    s += __int_as_float(__builtin_amdgcn_update_dpp(0, __float_as_int(s), 0x143, 0xc, 0xf, false));
    return s;
}

__global__ __launch_bounds__(BLOCK, 6) void socnet_kernel(
    const f32x4* __restrict__ X,      // (N, L) of 4-ch float4
    const float*  __restrict__ SC,    // (N, 4)
    const float*  __restrict__ wi1, const float* __restrict__ bi1,
    const float*  __restrict__ wi2, const float* __restrict__ bi2,
    const float*  __restrict__ we1, const float* __restrict__ be1,
    const float*  __restrict__ we2, const float* __restrict__ be2,
    f32x4* __restrict__ Y, int L)
{
    const int n    = blockIdx.x;          // one block per row
    const int tid  = threadIdx.x;
    const int lane = tid & 63;
    const int wid  = tid >> 6;

    const size_t rowoff = (size_t)n * (size_t)L;
    const f32x4* Xr = X + rowoff;
    f32x4*       Yr = Y + rowoff;

    // eta MLP weights (broadcast scalars)
    const float W10 = we1[0], W11 = we1[1], B1 = be1[0];
    const float W2  = we2[0], B2e = be2[0];

    // per-row scalars
    const float Q    = SC[n * 4 + 0];
    const float eta0 = SC[n * 4 + 1];
    const float R    = SC[n * 4 + 2];
    const float S3   = SC[n * 4 + 3];
    const float inv  = eta0 / (3600.0f * Q);

    // soc_init from X[n,0,:]
    const f32x4 x0 = Xr[0];
    const float h0 = sp(wi1[0] * x0.y + wi1[1] * x0.z + wi1[2] * x0.w + wi1[3] * R + bi1[0]);
    const float soc = S3 * (1.0f + (wi2[0] * h0 + bi2[0]));

    __shared__ f32x4 s_wsum[NTILES * NW];  // per-(tile,wave) totals
    __shared__ f32x4 s_offs[NTILES * NW];  // exclusive prefix of the above

    const int Lm1 = L - 1;

    // ---------------- Phase 1: scan tiles, no barriers, loads free-flow ----------
    f32x4 excl[NTILES];  // within-wave exclusive prefix per tile (static idx -> VGPRs)

    int p = tid;
    f32x4 xc = Xr[p];
    f32x4 xn = Xr[(p + 1 < L) ? (p + 1) : Lm1];

    #pragma unroll
    for (int t = 0; t < NTILES; ++t) {
        const int pn = p + BLOCK;
        f32x4 xc2, xn2;
        if (t < NTILES - 1) {              // prefetch next tile (never drained)
            xc2 = Xr[pn];
            xn2 = Xr[(pn + 1 < L) ? (pn + 1) : Lm1];
        }

        const float de_c = W2 * sp(W10 * xc.y + W11 * xc.z + B1) + B2e;
        const float de_n = W2 * sp(W10 * xn.y + W11 * xn.z + B1) + B2e;
        const float dy   = inv * (1.0f + de_c) * xc.y;

        f32x4 inc;
        inc.x = (xn.y - xc.y) * dy;
        inc.y = (xn.z - xc.z) * dy;
        inc.z = (xn.w - xc.w) * dy;
        inc.w = (de_n - de_c) * dy;

        f32x4 scn;
        scn.x = wave_scan_f32(inc.x);
        scn.y = wave_scan_f32(inc.y);
        scn.z = wave_scan_f32(inc.z);
        scn.w = wave_scan_f32(inc.w);

        excl[t] = scn - inc;
        if (lane == 63) s_wsum[t * NW + wid] = scn;

        xc = xc2; xn = xn2; p = pn;
    }

    __syncthreads();  // barrier #1

    // ---------------- Offset table: wave 0 scans the 64 (tile,wave) totals -------
    if (wid == 0) {
        const f32x4 v = s_wsum[lane];      // lane = t*NW + w
        f32x4 s;
        s.x = wave_scan_f32(v.x);
        s.y = wave_scan_f32(v.y);
        s.z = wave_scan_f32(v.z);
        s.w = wave_scan_f32(v.w);
        s_offs[lane] = s - v;              // exclusive
    }

    __syncthreads();  // barrier #2

    // ---------------- Phase 2: add offsets, store; no barriers -------------------
    #pragma unroll
    for (int t = 0; t < NTILES; ++t) {
        const f32x4 off = s_offs[t * NW + wid];   // wave-uniform -> broadcast read
        const f32x4 yv  = off + excl[t] + (f32x4)(soc);
        __builtin_nontemporal_store(yv, &Yr[t * BLOCK + tid]);
    }
}

extern "C" void kernel_launch(void* const* d_in, const int* in_sizes, int n_in,
                              void* d_out, int out_size, void* d_ws, size_t ws_size,
                              hipStream_t stream) {
    const f32x4* X   = (const f32x4*)d_in[0];
    const float* SC  = (const float*)d_in[1];
    const float* wi1 = (const float*)d_in[2];
    const float* bi1 = (const float*)d_in[3];
    const float* wi2 = (const float*)d_in[4];
    const float* bi2 = (const float*)d_in[5];
    const float* we1 = (const float*)d_in[6];
    const float* be1 = (const float*)d_in[7];
    const float* we2 = (const float*)d_in[8];
    const float* be2 = (const float*)d_in[9];
    f32x4* Y = (f32x4*)d_out;

    const int N = in_sizes[1] / 4;           // SC is (N,4)
    const int L = in_sizes[0] / (4 * N);     // X is (N,L,4); L = 4096 = BLOCK*NTILES

    socnet_kernel<<<N, BLOCK, 0, stream>>>(X, SC, wi1, bi1, wi2, bi2,
                                           we1, be1, we2, be2, Y, L);
}

// Round 10
// 93.541 us; speedup vs baseline: 1.1712x; 1.1712x over previous
//
#include <hip/hip_runtime.h>
#include <math.h>

#define BLOCK 256
#define NW (BLOCK / 64)

typedef float f32x4 __attribute__((ext_vector_type(4)));

__device__ __forceinline__ float sp(float x) {
    // softplus: max(x,0) + log(1 + exp(-|x|)) — fast intrinsics, huge error budget
    return fmaxf(x, 0.0f) + __logf(1.0f + __expf(-fabsf(x)));
}

// Wave64 inclusive scan (add) on the VALU via DPP (verified rounds 7-9).
__device__ __forceinline__ float wave_scan_f32(float s) {
    s += __int_as_float(__builtin_amdgcn_update_dpp(0, __float_as_int(s), 0x111, 0xf, 0xf, false));
    s += __int_as_float(__builtin_amdgcn_update_dpp(0, __float_as_int(s), 0x112, 0xf, 0xf, false));
    s += __int_as_float(__builtin_amdgcn_update_dpp(0, __float_as_int(s), 0x114, 0xf, 0xf, false));
    s += __int_as_float(__builtin_amdgcn_update_dpp(0, __float_as_int(s), 0x118, 0xf, 0xf, false));
    s += __int_as_float(__builtin_amdgcn_update_dpp(0, __float_as_int(s), 0x142, 0xa, 0xf, false));
    s += __int_as_float(__builtin_amdgcn_update_dpp(0, __float_as_int(s), 0x143, 0xc, 0xf, false));
    return s;
}

// Barrier that waits ONLY on LDS ops — prefetched global loads stay in flight.
// (__syncthreads() would emit s_waitcnt vmcnt(0) and drain them: the structural
// stall identified in the guide. Correctness here needs only LDS visibility.)
__device__ __forceinline__ void lds_barrier() {
    asm volatile("s_waitcnt lgkmcnt(0)\n\ts_barrier" ::: "memory");
}

__global__ __launch_bounds__(BLOCK) void socnet_kernel(
    const f32x4* __restrict__ X,      // (N, L) of 4-ch float4
    const float*  __restrict__ SC,    // (N, 4)
    const float*  __restrict__ wi1, const float* __restrict__ bi1,
    const float*  __restrict__ wi2, const float* __restrict__ bi2,
    const float*  __restrict__ we1, const float* __restrict__ be1,
    const float*  __restrict__ we2, const float* __restrict__ be2,
    f32x4* __restrict__ Y, int L)
{
    const int n    = blockIdx.x;
    const int t    = threadIdx.x;
    const int wid  = t >> 6;

    const size_t rowoff = (size_t)n * (size_t)L;
    const f32x4* Xr = X + rowoff;
    f32x4*       Yr = Y + rowoff;

    // eta MLP weights (broadcast scalars)
    const float W10 = we1[0], W11 = we1[1], B1 = be1[0];
    const float W2  = we2[0], B2e = be2[0];

    // per-row scalars
    const float Q    = SC[n * 4 + 0];
    const float eta0 = SC[n * 4 + 1];
    const float R    = SC[n * 4 + 2];
    const float S3   = SC[n * 4 + 3];
    const float inv  = eta0 / (3600.0f * Q);

    // soc_init from X[n,0,:] — all threads redundantly (cached load)
    const f32x4 x0 = Xr[0];
    const float h0 = sp(wi1[0] * x0.y + wi1[1] * x0.z + wi1[2] * x0.w + wi1[3] * R + bi1[0]);
    const float soc = S3 * (1.0f + (wi2[0] * h0 + bi2[0]));

    __shared__ f32x4 s_wsum[2][NW];  // double-buffered per-wave scan totals

    f32x4 carry = (f32x4)(0.0f);

    const int ntiles = L / BLOCK;  // 16
    const int Lm1 = L - 1;

    // ---- depth-2 software pipeline; loads stay in flight across lds_barrier ----
    int p = t;
    f32x4 xc0 = Xr[p];
    f32x4 xn0 = Xr[(p + 1 < L) ? (p + 1) : Lm1];
    f32x4 xc1 = Xr[(p + BLOCK < L) ? (p + BLOCK) : Lm1];
    f32x4 xn1 = Xr[(p + BLOCK + 1 < L) ? (p + BLOCK + 1) : Lm1];

    for (int tile = 0; tile < ntiles; ++tile) {
        // issue tile+2's loads now (2 tile-periods of cover, never drained)
        const int pc = (p + 2 * BLOCK < L) ? (p + 2 * BLOCK) : Lm1;
        const int pn = (p + 2 * BLOCK + 1 < L) ? (p + 2 * BLOCK + 1) : Lm1;
        const f32x4 xc2 = Xr[pc];
        const f32x4 xn2 = Xr[pn];

        // delta_eta at p and p+1
        const float de_c = W2 * sp(W10 * xc0.y + W11 * xc0.z + B1) + B2e;
        const float de_n = W2 * sp(W10 * xn0.y + W11 * xn0.z + B1) + B2e;
        const float dy   = inv * (1.0f + de_c) * xc0.y;

        // inc[p] = (obs[p+1] - obs[p]) * dy;  obs = (I, T, U, delta_eta)
        f32x4 inc;
        inc.x = (xn0.y - xc0.y) * dy;
        inc.y = (xn0.z - xc0.z) * dy;
        inc.z = (xn0.w - xc0.w) * dy;
        inc.w = (de_n - de_c) * dy;

        // 64-lane inclusive scan, 4 fp32 channels, all on the VALU
        f32x4 scn;
        scn.x = wave_scan_f32(inc.x);
        scn.y = wave_scan_f32(inc.y);
        scn.z = wave_scan_f32(inc.z);
        scn.w = wave_scan_f32(inc.w);

        if ((t & 63) == 63) s_wsum[tile & 1][wid] = scn;
        lds_barrier();  // LDS-only wait: prefetched global loads NOT drained

        // exclusive prefix at p = carry + prev-wave totals + (scn - inc)
        f32x4 excl = carry + scn - inc;
        #pragma unroll
        for (int w = 0; w < NW; ++w) {
            const f32x4 ws = s_wsum[tile & 1][w];
            if (w < wid) excl += ws;
            carry += ws;
        }

        // y[p] = soc + exclusive_prefix(p); coalesced nontemporal store
        const f32x4 yv = excl + (f32x4)(soc);
        __builtin_nontemporal_store(yv, &Yr[p]);

        // rotate pipeline registers
        xc0 = xc1; xn0 = xn1;
        xc1 = xc2; xn1 = xn2;
        p += BLOCK;
    }
}

extern "C" void kernel_launch(void* const* d_in, const int* in_sizes, int n_in,
                              void* d_out, int out_size, void* d_ws, size_t ws_size,
                              hipStream_t stream) {
    const f32x4* X   = (const f32x4*)d_in[0];
    const float* SC  = (const float*)d_in[1];
    const float* wi1 = (const float*)d_in[2];
    const float* bi1 = (const float*)d_in[3];
    const float* wi2 = (const float*)d_in[4];
    const float* bi2 = (const float*)d_in[5];
    const float* we1 = (const float*)d_in[6];
    const float* be1 = (const float*)d_in[7];
    const float* we2 = (const float*)d_in[8];
    const float* be2 = (const float*)d_in[9];
    f32x4* Y = (f32x4*)d_out;

    const int N = in_sizes[1] / 4;           // SC is (N,4)
    const int L = in_sizes[0] / (4 * N);     // X is (N,L,4)

    socnet_kernel<<<N, BLOCK, 0, stream>>>(X, SC, wi1, bi1, wi2, bi2,
                                           we1, be1, we2, be2, Y, L);
}

// Round 11
// 88.727 us; speedup vs baseline: 1.2347x; 1.0543x over previous
//
#include <hip/hip_runtime.h>
#include <math.h>

#define BLOCK 256
#define NW (BLOCK / 64)

typedef float f32x4 __attribute__((ext_vector_type(4)));

__device__ __forceinline__ float sp(float x) {
    // softplus: max(x,0) + log(1 + exp(-|x|)) — fast intrinsics, huge error budget
    return fmaxf(x, 0.0f) + __logf(1.0f + __expf(-fabsf(x)));
}

// Wave64 inclusive scan (add) on the VALU via DPP (verified rounds 7-10).
__device__ __forceinline__ float wave_scan_f32(float s) {
    s += __int_as_float(__builtin_amdgcn_update_dpp(0, __float_as_int(s), 0x111, 0xf, 0xf, false));
    s += __int_as_float(__builtin_amdgcn_update_dpp(0, __float_as_int(s), 0x112, 0xf, 0xf, false));
    s += __int_as_float(__builtin_amdgcn_update_dpp(0, __float_as_int(s), 0x114, 0xf, 0xf, false));
    s += __int_as_float(__builtin_amdgcn_update_dpp(0, __float_as_int(s), 0x118, 0xf, 0xf, false));
    s += __int_as_float(__builtin_amdgcn_update_dpp(0, __float_as_int(s), 0x142, 0xa, 0xf, false));
    s += __int_as_float(__builtin_amdgcn_update_dpp(0, __float_as_int(s), 0x143, 0xc, 0xf, false));
    return s;
}

// Barrier waiting only on LDS ops (global prefetches stay in flight).
__device__ __forceinline__ void lds_barrier() {
    asm volatile("s_waitcnt lgkmcnt(0)\n\ts_barrier" ::: "memory");
}

__global__ __launch_bounds__(BLOCK) void socnet_kernel(
    const f32x4* __restrict__ X,      // (N, L) of 4-ch float4
    const float*  __restrict__ SC,    // (N, 4)
    const float*  __restrict__ wi1, const float* __restrict__ bi1,
    const float*  __restrict__ wi2, const float* __restrict__ bi2,
    const float*  __restrict__ we1, const float* __restrict__ be1,
    const float*  __restrict__ we2, const float* __restrict__ be2,
    f32x4* __restrict__ Y, int L)
{
    const int n    = blockIdx.x;
    const int t    = threadIdx.x;
    const int wid  = t >> 6;

    const size_t rowoff = (size_t)n * (size_t)L;
    const f32x4* Xr = X + rowoff;
    f32x4*       Yr = Y + rowoff;

    // eta MLP weights (broadcast scalars)
    const float W10 = we1[0], W11 = we1[1], B1 = be1[0];
    const float W2  = we2[0], B2e = be2[0];

    // per-row scalars
    const float Q    = SC[n * 4 + 0];
    const float eta0 = SC[n * 4 + 1];
    const float R    = SC[n * 4 + 2];
    const float S3   = SC[n * 4 + 3];
    const float inv  = eta0 / (3600.0f * Q);

    // soc_init from X[n,0,:]
    const f32x4 x0 = Xr[0];
    const float h0 = sp(wi1[0] * x0.y + wi1[1] * x0.z + wi1[2] * x0.w + wi1[3] * R + bi1[0]);
    const float soc = S3 * (1.0f + (wi2[0] * h0 + bi2[0]));

    // s_obs[b][i] = obs(I,T,U,de) for elements [tile*256 .. tile*256+256] (257 entries)
    __shared__ f32x4 s_obs[2][BLOCK + 1];
    __shared__ f32x4 s_wsum[2][NW];

    f32x4 carry = (f32x4)(0.0f);

    const int ntiles = L / BLOCK;  // 16
    const int Lm1 = L - 1;

    // pipeline registers: xc0=tile k, xc1=tile k+1, xc2=tile k+2 (clamped at tail)
    int p = t;
    f32x4 xc0 = Xr[p];
    f32x4 xc1 = Xr[(p + BLOCK     <= Lm1) ? p + BLOCK     : Lm1];
    f32x4 xc2 = Xr[(p + 2 * BLOCK <= Lm1) ? p + 2 * BLOCK : Lm1];

    // de for own tile-0 element; populate s_obs[0] (tile 0's neighbor table)
    float de0 = W2 * sp(W10 * xc0.y + W11 * xc0.z + B1) + B2e;
    {
        f32x4 ob; ob.x = xc0.y; ob.y = xc0.z; ob.z = xc0.w; ob.w = de0;
        s_obs[0][t] = ob;
        if (t == 0) {
            const float d = W2 * sp(W10 * xc1.y + W11 * xc1.z + B1) + B2e;
            f32x4 ob2; ob2.x = xc1.y; ob2.y = xc1.z; ob2.z = xc1.w; ob2.w = d;
            s_obs[0][BLOCK] = ob2;  // element 256 (tile-0 boundary)
        }
    }
    lds_barrier();

    for (int tile = 0; tile < ntiles; ++tile) {
        // global prefetch tile+3 (stays in flight; barriers don't drain vmcnt)
        int ip = p + 3 * BLOCK; if (ip > Lm1) ip = Lm1;
        const f32x4 xc3 = Xr[ip];

        // neighbor obs[p+1] from table written during previous tile (issue early)
        const f32x4 nb = s_obs[tile & 1][t + 1];

        // ahead-compute NEXT tile's obs into the other buffer (one sp per element)
        const float de1 = W2 * sp(W10 * xc1.y + W11 * xc1.z + B1) + B2e;
        {
            f32x4 ob; ob.x = xc1.y; ob.y = xc1.z; ob.z = xc1.w; ob.w = de1;
            s_obs[(tile + 1) & 1][t] = ob;
            if (t == 0) {
                const float d2 = W2 * sp(W10 * xc2.y + W11 * xc2.z + B1) + B2e;
                f32x4 ob2; ob2.x = xc2.y; ob2.y = xc2.z; ob2.z = xc2.w; ob2.w = d2;
                s_obs[(tile + 1) & 1][BLOCK] = ob2;  // element (tile+2)*256
            }
        }

        // inc[p] = (obs[p+1] - obs[p]) * dy
        const float dy = inv * (1.0f + de0) * xc0.y;
        f32x4 inc;
        inc.x = (nb.x - xc0.y) * dy;
        inc.y = (nb.y - xc0.z) * dy;
        inc.z = (nb.z - xc0.w) * dy;
        inc.w = (nb.w - de0)  * dy;

        // 64-lane inclusive scan, 4 fp32 channels, on the VALU
        f32x4 scn;
        scn.x = wave_scan_f32(inc.x);
        scn.y = wave_scan_f32(inc.y);
        scn.z = wave_scan_f32(inc.z);
        scn.w = wave_scan_f32(inc.w);

        if ((t & 63) == 63) s_wsum[tile & 1][wid] = scn;
        lds_barrier();  // fences: s_obs handoff + s_wsum publication

        // exclusive prefix at p = carry + prev-wave totals + (scn - inc)
        f32x4 excl = carry + scn - inc;
        #pragma unroll
        for (int w = 0; w < NW; ++w) {
            const f32x4 ws = s_wsum[tile & 1][w];
            if (w < wid) excl += ws;
            carry += ws;
        }

        // y[p] = soc + exclusive prefix; coalesced nontemporal store
        const f32x4 yv = excl + (f32x4)(soc);
        __builtin_nontemporal_store(yv, &Yr[p]);

        // rotate pipeline
        xc0 = xc1; de0 = de1;
        xc1 = xc2;
        xc2 = xc3;
        p += BLOCK;
    }
}

extern "C" void kernel_launch(void* const* d_in, const int* in_sizes, int n_in,
                              void* d_out, int out_size, void* d_ws, size_t ws_size,
                              hipStream_t stream) {
    const f32x4* X   = (const f32x4*)d_in[0];
    const float* SC  = (const float*)d_in[1];
    const float* wi1 = (const float*)d_in[2];
    const float* bi1 = (const float*)d_in[3];
    const float* wi2 = (const float*)d_in[4];
    const float* bi2 = (const float*)d_in[5];
    const float* we1 = (const float*)d_in[6];
    const float* be1 = (const float*)d_in[7];
    const float* we2 = (const float*)d_in[8];
    const float* be2 = (const float*)d_in[9];
    f32x4* Y = (f32x4*)d_out;

    const int N = in_sizes[1] / 4;           // SC is (N,4)
    const int L = in_sizes[0] / (4 * N);     // X is (N,L,4)

    socnet_kernel<<<N, BLOCK, 0, stream>>>(X, SC, wi1, bi1, wi2, bi2,
                                           we1, be1, we2, be2, Y, L);
}